// Round 5
// baseline (806.718 us; speedup 1.0000x reference)
//
#include <hip/hip_runtime.h>

#define DIMC   2560
#define NHEADS 40
#define HDIM   64
#define BATCH  2
#define SEQ    2048
#define MROWS  (BATCH*SEQ)   // 4096
#define THREEC (3*DIMC)      // 7680

typedef short bf16x8 __attribute__((ext_vector_type(8)));
typedef float f32x4  __attribute__((ext_vector_type(4)));

static __device__ __forceinline__ unsigned short f2bf(float f) {
    unsigned int u = __float_as_uint(f);
    u += 0x7FFF + ((u >> 16) & 1);   // round-to-nearest-even
    return (unsigned short)(u >> 16);
}

// pack two f32 -> two bf16 in one dword: round-to-nearest (ties away) via
// +0x8000 on the bit pattern, then v_perm_b32 grabs the high halves.
static __device__ __forceinline__ unsigned int pkbf(float a, float b) {
    unsigned int ua = __float_as_uint(a) + 0x8000u;
    unsigned int ub = __float_as_uint(b) + 0x8000u;
    return __builtin_amdgcn_perm(ub, ua, 0x07060302u);
}

static __device__ __forceinline__ void gload_lds16(const ushort* g, ushort* l) {
    __builtin_amdgcn_global_load_lds(
        (const __attribute__((address_space(1))) void*)g,
        (__attribute__((address_space(3))) void*)l, 16, 0, 0);
}

__global__ void cast_f32_bf16(const float* __restrict__ src, ushort* __restrict__ dst, int n4) {
    int i = blockIdx.x * blockDim.x + threadIdx.x;
    if (i < n4) {
        float4 v = ((const float4*)src)[i];
        uint2 o = {pkbf(v.x, v.y), pkbf(v.z, v.w)};
        ((uint2*)dst)[i] = o;
    }
}

// W [K,N] f32 -> WT [N,K] bf16, 64x64 tiles through LDS
__global__ __launch_bounds__(256) void transpose_cast(
    const float* __restrict__ W, ushort* __restrict__ WT, int K, int N)
{
    __shared__ float Ls[64][65];
    const int t = threadIdx.x;
    const int n0 = blockIdx.x * 64, k0 = blockIdx.y * 64;
    #pragma unroll
    for (int p = 0; p < 4; ++p) {
        int idx = p * 256 + t;
        int r = idx >> 4, c4 = (idx & 15) * 4;
        float4 v = *(const float4*)(W + (size_t)(k0 + r) * N + n0 + c4);
        Ls[r][c4] = v.x; Ls[r][c4 + 1] = v.y; Ls[r][c4 + 2] = v.z; Ls[r][c4 + 3] = v.w;
    }
    __syncthreads();
    #pragma unroll
    for (int p = 0; p < 4; ++p) {
        int idx = p * 256 + t;
        int n = idx >> 4, kc = (idx & 15) * 4;
        uint2 o = {pkbf(Ls[kc][n], Ls[kc + 1][n]), pkbf(Ls[kc + 2][n], Ls[kc + 3][n])};
        *(uint2*)(WT + (size_t)(n0 + n) * K + k0 + kc) = o;
    }
}

// C = A(bf16 [M,K]) * BT(bf16 [N,K])^T + bias — m97 structure (unchanged).
template<int MODE>
__global__ __launch_bounds__(256) void gemm_bt(
    const ushort* __restrict__ A, const ushort* __restrict__ BT,
    const float* __restrict__ bias,
    ushort* __restrict__ q_out, ushort* __restrict__ k_out, ushort* __restrict__ v_out,
    float* __restrict__ c_out, int M, int N, int K)
{
    __shared__ __align__(16) ushort As[128 * 32];
    __shared__ __align__(16) ushort Bs[128 * 32];
    const int tid  = threadIdx.x;
    const int lane = tid & 63;
    const int wave = tid >> 6;
    const int l15  = lane & 15, quad = lane >> 4;
    const int wm = (wave >> 1) * 64;
    const int wn = (wave & 1) * 64;
    const int m0 = blockIdx.y * 128;
    const int n0 = blockIdx.x * 128;

    const int srow = wave * 32 + (lane >> 2);
    const int scol = (lane & 3) * 8;
    const ushort* ga = A  + (size_t)(m0 + srow) * K + scol;
    const ushort* gb = BT + (size_t)(n0 + srow) * K + scol;
    ushort* la = &As[(wave * 32) * 32];
    ushort* lb = &Bs[(wave * 32) * 32];

    f32x4 acc[4][4] = {};

    for (int k0 = 0; k0 < K; k0 += 32) {
        __syncthreads();
        #pragma unroll
        for (int p = 0; p < 2; ++p) {
            gload_lds16(ga + k0 + (size_t)(p * 16) * K, la + p * 16 * 32);
            gload_lds16(gb + k0 + (size_t)(p * 16) * K, lb + p * 16 * 32);
        }
        __syncthreads();
        bf16x8 af[4], bfr[4];
        #pragma unroll
        for (int i = 0; i < 4; ++i)
            af[i] = *(const bf16x8*)&As[(wm + i * 16 + l15) * 32 + quad * 8];
        #pragma unroll
        for (int j = 0; j < 4; ++j)
            bfr[j] = *(const bf16x8*)&Bs[(wn + j * 16 + l15) * 32 + quad * 8];
        #pragma unroll
        for (int i = 0; i < 4; ++i)
            #pragma unroll
            for (int j = 0; j < 4; ++j)
                acc[i][j] = __builtin_amdgcn_mfma_f32_16x16x32_bf16(af[i], bfr[j], acc[i][j], 0, 0, 0);
    }

    const int rbase = m0 + wm + (quad << 2);
    const int cbase = n0 + wn + l15;
    #pragma unroll
    for (int i = 0; i < 4; ++i) {
        #pragma unroll
        for (int j = 0; j < 4; ++j) {
            int ccol = cbase + j * 16;
            float bv = bias[ccol];
            #pragma unroll
            for (int r = 0; r < 4; ++r) {
                int row = rbase + i * 16 + r;
                float val = acc[i][j][r] + bv;
                if (MODE == 0) {
                    int which = ccol / DIMC;
                    int cc = ccol - which * DIMC;
                    int h = cc >> 6, d = cc & 63;
                    int b = row >> 11, n = row & 2047;
                    if (which == 0) {
                        size_t idx = (((size_t)(b * NHEADS + h)) * SEQ + n) * HDIM + d;
                        q_out[idx] = f2bf(val * 0.18033688011112042f);  // 0.125*log2(e)
                    } else if (which == 1) {
                        size_t idx = (((size_t)(b * NHEADS + h)) * SEQ + n) * HDIM + d;
                        k_out[idx] = f2bf(val);
                    } else {
                        size_t idx = (((size_t)(b * NHEADS + h)) * HDIM + d) * SEQ + n;  // V^T
                        v_out[idx] = f2bf(val);
                    }
                } else {
                    c_out[(size_t)row * N + ccol] = val;
                }
            }
        }
    }
}

// Flash attention, static-max softmax. 1D grid with XCD-pinned head mapping:
// WG i -> XCD i%8 (round-robin dispatch); we decode bh = (i&7) + 8*(i>>7) so
// all 16 q-tiles of a head land on ONE XCD -> its K+V (512 KB) stays in that
// XCD's 4 MB L2 -> 16x reuse, L2-hit latency instead of HBM-miss latency.
__global__ __launch_bounds__(256) void attn_kernel(
    const ushort* __restrict__ Q, const ushort* __restrict__ K,
    const ushort* __restrict__ VT, ushort* __restrict__ Oattn)
{
    __shared__ __align__(16) ushort Ps[128][88];
    const int tid  = threadIdx.x;
    const int lane = tid & 63;
    const int quad = lane >> 4;
    const int l15  = lane & 15;
    const int wave = tid >> 6;
    const int gid  = blockIdx.x;
    const int bh = (gid & 7) + 8 * (gid >> 7);         // head index, XCD-pinned
    const int q0 = ((gid >> 3) & 15) * 128;            // q-tile
    const int b = bh / NHEADS, h = bh % NHEADS;
    const int wq = wave * 32;
    const size_t base = (size_t)bh * SEQ * HDIM;
    const ushort* Kb = K + base;
    const ushort* Vb = VT + base;

    bf16x8 qf[2][2];
    #pragma unroll
    for (int i = 0; i < 2; ++i)
        #pragma unroll
        for (int kk = 0; kk < 2; ++kk)
            qf[i][kk] = *(const bf16x8*)(Q + base + (size_t)(q0 + wq + i * 16 + l15) * HDIM
                                         + kk * 32 + quad * 8);

    float lsum[2] = {0.f, 0.f};
    f32x4 o[4][2] = {};   // O^T: rows d = dj*16+quad*4+r, col q = l15

    // prefetch K tile 0
    bf16x8 kf[4][2];
    #pragma unroll
    for (int j = 0; j < 4; ++j)
        #pragma unroll
        for (int kk = 0; kk < 2; ++kk)
            kf[j][kk] = *(const bf16x8*)(Kb + (size_t)(j * 16 + l15) * HDIM + kk * 32 + quad * 8);

    for (int t = 0; t < SEQ / 64; ++t) {
        const int k0 = t * 64;
        // S^T = K Q^T
        f32x4 s[2][4] = {};
        #pragma unroll
        for (int j = 0; j < 4; ++j)
            #pragma unroll
            for (int kk = 0; kk < 2; ++kk)
                #pragma unroll
                for (int i = 0; i < 2; ++i)
                    s[i][j] = __builtin_amdgcn_mfma_f32_16x16x32_bf16(kf[j][kk], qf[i][kk], s[i][j], 0, 0, 0);
        // V fragments for this tile
        bf16x8 vf[4][2];
        #pragma unroll
        for (int dj = 0; dj < 4; ++dj)
            #pragma unroll
            for (int kk = 0; kk < 2; ++kk)
                vf[dj][kk] = *(const bf16x8*)(Vb + (size_t)(dj * 16 + l15) * SEQ
                                              + k0 + kk * 32 + quad * 8);
        // K fragments for next tile (WAR reuse of kf)
        const int k0n = ((t + 1) & (SEQ / 64 - 1)) * 64;
        #pragma unroll
        for (int j = 0; j < 4; ++j)
            #pragma unroll
            for (int kk = 0; kk < 2; ++kk)
                kf[j][kk] = *(const bf16x8*)(Kb + (size_t)(k0n + j * 16 + l15) * HDIM
                                             + kk * 32 + quad * 8);
        // p = exp2(s); per-lane l partial; packed store to LDS
        #pragma unroll
        for (int i = 0; i < 2; ++i)
            #pragma unroll
            for (int j = 0; j < 4; ++j) {
                float p0 = __builtin_amdgcn_exp2f(s[i][j][0]);
                float p1 = __builtin_amdgcn_exp2f(s[i][j][1]);
                float p2 = __builtin_amdgcn_exp2f(s[i][j][2]);
                float p3 = __builtin_amdgcn_exp2f(s[i][j][3]);
                lsum[i] += (p0 + p1) + (p2 + p3);
                uint2 pk = {pkbf(p0, p1), pkbf(p2, p3)};
                *(uint2*)&Ps[wq + i * 16 + l15][j * 16 + quad * 4] = pk;
            }
        // O^T += V^T P
        #pragma unroll
        for (int kk = 0; kk < 2; ++kk) {
            bf16x8 pf[2];
            #pragma unroll
            for (int i = 0; i < 2; ++i)
                pf[i] = *(const bf16x8*)&Ps[wq + i * 16 + l15][kk * 32 + quad * 8];
            #pragma unroll
            for (int dj = 0; dj < 4; ++dj)
                #pragma unroll
                for (int i = 0; i < 2; ++i)
                    o[dj][i] = __builtin_amdgcn_mfma_f32_16x16x32_bf16(vf[dj][kk], pf[i], o[dj][i], 0, 0, 0);
        }
    }
    // reduce l over quad groups once
    #pragma unroll
    for (int i = 0; i < 2; ++i) {
        lsum[i] += __shfl_xor(lsum[i], 16, 64);
        lsum[i] += __shfl_xor(lsum[i], 32, 64);
    }
    #pragma unroll
    for (int i = 0; i < 2; ++i) {
        float inv = 1.f / lsum[i];
        int qrow = q0 + wq + i * 16 + l15;
        size_t orow = ((size_t)b * SEQ + qrow) * DIMC + (size_t)h * HDIM;
        #pragma unroll
        for (int dj = 0; dj < 4; ++dj) {
            uint2 ok = {pkbf(o[dj][i][0] * inv, o[dj][i][1] * inv),
                        pkbf(o[dj][i][2] * inv, o[dj][i][3] * inv)};
            *(uint2*)(Oattn + orow + dj * 16 + quad * 4) = ok;
        }
    }
}

extern "C" void kernel_launch(void* const* d_in, const int* in_sizes, int n_in,
                              void* d_out, int out_size, void* d_ws, size_t ws_size,
                              hipStream_t stream) {
    const float* x      = (const float*)d_in[0];
    const float* w_qkv  = (const float*)d_in[1];
    const float* b_qkv  = (const float*)d_in[2];
    const float* w_proj = (const float*)d_in[3];
    const float* b_proj = (const float*)d_in[4];
    float* out = (float*)d_out;

    char* p = (char*)d_ws;
    const size_t sz_x   = (size_t)MROWS * DIMC * 2;
    const size_t sz_qkv = (size_t)BATCH * NHEADS * SEQ * HDIM * 2;
    ushort* xb    = (ushort*)p;  p += sz_x;
    ushort* Qb    = (ushort*)p;  p += sz_qkv;
    ushort* Kb    = (ushort*)p;  p += sz_qkv;
    ushort* Vtb   = (ushort*)p;  p += sz_qkv;
    ushort* wqkvT = (ushort*)p;  p += (size_t)THREEC * DIMC * 2;
    ushort* attnb  = xb;
    ushort* wprojT = Qb;

    int n4 = MROWS * DIMC / 4;
    cast_f32_bf16<<<n4 / 256, 256, 0, stream>>>(x, xb, n4);

    transpose_cast<<<dim3(THREEC / 64, DIMC / 64), 256, 0, stream>>>(w_qkv, wqkvT, DIMC, THREEC);

    gemm_bt<0><<<dim3(THREEC / 128, MROWS / 128), 256, 0, stream>>>(
        xb, wqkvT, b_qkv, Qb, Kb, Vtb, nullptr, MROWS, THREEC, DIMC);

    attn_kernel<<<1280, 256, 0, stream>>>(Qb, Kb, Vtb, attnb);

    transpose_cast<<<dim3(DIMC / 64, DIMC / 64), 256, 0, stream>>>(w_proj, wprojT, DIMC, DIMC);

    gemm_bt<1><<<dim3(DIMC / 128, MROWS / 128), 256, 0, stream>>>(
        attnb, wprojT, b_proj, nullptr, nullptr, nullptr, out, MROWS, DIMC, DIMC);
}